// Round 6
// baseline (81.173 us; speedup 1.0000x reference)
//
#include <hip/hip_runtime.h>
#include <math.h>

#define NE 64
#define ND 512
#define NH 1024
#define NT 256
#define NC 8   // token slots per fc1 pass (pad amount in build_group)

// ws layout: h[NT*NH] floats

__device__ __forceinline__ int build_group(const int* __restrict__ idx, int e,
                                           int* tok_lds, int* wsum) {
    const int t = threadIdx.x, wave = t >> 6, lane = t & 63;
    const bool m = (idx[t] == e);
    const unsigned long long mask = __ballot(m);
    if (lane == 0) wsum[wave] = __popcll(mask);
    __syncthreads();
    int before = 0;
#pragma unroll
    for (int w = 0; w < 3; ++w) before += (w < wave) ? wsum[w] : 0;
    const int nt = wsum[0] + wsum[1] + wsum[2] + wsum[3];
    if (m) {
        int pos = before + __popcll(mask & ((1ull << lane) - 1ull));
        tok_lds[pos] = t;
    }
    __syncthreads();
    // pad so fragment loads are unconditional (dupes of token 0; stores stay
    // guarded by nt, so pad results are discarded)
    if (nt > 0 && t >= nt && t < nt + NC) tok_lds[t] = tok_lds[0];
    __syncthreads();
    return nt;
}

// Fused butterfly over 8 accumulators: 10 shuffles, depth 6, for 8 full
// 64-lane reductions. On exit lanes 0..7 hold the sum for token bitrev3(lane).
__device__ __forceinline__ float fused_reduce8_64(float v[NC], int lane) {
#pragma unroll
    for (int i = 0; i < 4; ++i) {
        float lo = v[i], hi = v[i + 4];
        float send = (lane & 1) ? lo : hi;
        float recv = __shfl_xor(send, 1);
        v[i] = ((lane & 1) ? hi : lo) + recv;
    }
#pragma unroll
    for (int i = 0; i < 2; ++i) {
        float lo = v[i], hi = v[i + 2];
        float send = (lane & 2) ? lo : hi;
        float recv = __shfl_xor(send, 2);
        v[i] = ((lane & 2) ? hi : lo) + recv;
    }
    {
        float lo = v[0], hi = v[1];
        float send = (lane & 4) ? lo : hi;
        float recv = __shfl_xor(send, 4);
        v[0] = ((lane & 4) ? hi : lo) + recv;
    }
    v[0] += __shfl_xor(v[0], 8);
    v[0] += __shfl_xor(v[0], 16);
    v[0] += __shfl_xor(v[0], 32);
    return v[0];
}

// Fused butterfly over 4 accumulators -> full 64-lane sums.
// On exit lane l holds the sum for token t = 2*(l&1) + ((l>>1)&1).
__device__ __forceinline__ float fused_reduce4_64(float v[4], int lane) {
#pragma unroll
    for (int i = 0; i < 2; ++i) {
        float lo = v[i], hi = v[i + 2];
        float send = (lane & 1) ? lo : hi;
        float recv = __shfl_xor(send, 1);
        v[i] = ((lane & 1) ? hi : lo) + recv;
    }
    {
        float lo = v[0], hi = v[1];
        float send = (lane & 2) ? lo : hi;
        float recv = __shfl_xor(send, 2);
        v[0] = ((lane & 2) ? hi : lo) + recv;
    }
    v[0] += __shfl_xor(v[0], 4);
    v[0] += __shfl_xor(v[0], 8);
    v[0] += __shfl_xor(v[0], 16);
    v[0] += __shfl_xor(v[0], 32);
    return v[0];
}

// fc1: grid = 64*32*2. Block (e, ch, tc): 32 H-rows (4 waves x 8 rows),
// token slots [8*tc, 8*tc+8) (stride-16 loop as overflow safety).
// Lane covers k in [4l,4l+4) and [256+4l,256+4l+4)  (coalesced 1KB/instr).
__global__ __launch_bounds__(256) void fc1_kernel(
    const float* __restrict__ x, const float* __restrict__ w1,
    const int* __restrict__ idx, float* __restrict__ h) {
    __shared__ int tok_lds[NT + NC];
    __shared__ int wsum[4];
    const int b  = blockIdx.x;
    const int tc = b & 1;
    const int e  = (b >> 1) & 63;
    const int ch = b >> 7;
    const int tid = threadIdx.x, wave = tid >> 6, lane = tid & 63;
    const int nt = build_group(idx, e, tok_lds, wsum);
    const int start = tc * 8;
    if (start >= nt) return;
    const float* w1e = w1 + (size_t)e * NH * ND;
    const int jw = ch * 32 + wave * 8;

    for (int base = start; base < nt; base += 16) {
        float4 xa[NC], xb[NC];
#pragma unroll
        for (int t = 0; t < NC; ++t) {
            const float* xr = x + (size_t)tok_lds[base + t] * ND;
            xa[t] = *(const float4*)(xr + lane * 4);
            xb[t] = *(const float4*)(xr + 256 + lane * 4);
        }
#pragma unroll 4
        for (int r = 0; r < 8; ++r) {
            const float* wr = w1e + (size_t)(jw + r) * ND;
            const float4 wa = *(const float4*)(wr + lane * 4);
            const float4 wb = *(const float4*)(wr + 256 + lane * 4);
            float acc[NC];
#pragma unroll
            for (int t = 0; t < NC; ++t) {
                acc[t] = wa.x * xa[t].x + wa.y * xa[t].y + wa.z * xa[t].z + wa.w * xa[t].w
                       + wb.x * xb[t].x + wb.y * xb[t].y + wb.z * xb[t].z + wb.w * xb[t].w;
            }
            float p = fused_reduce8_64(acc, lane);
            if (lane < NC) {
                int t = ((lane & 1) << 2) | (lane & 2) | ((lane >> 2) & 1);
                if (base + t < nt) {
                    int tk = tok_lds[base + t];
                    float s = p / (1.0f + __expf(-p));
                    h[(size_t)tk * NH + (jw + r)] = s;
                }
            }
        }
    }
}

// fc2: grid = 64*32*2. Block (e, ch, th): 16 D-rows; each wave owns 4 d-rows
// and ALL of this block's <=4 token slots [4*th, 4*th+4) (stride-8 safety
// loop). All 4 waves stream weights regardless of nt.
// Lane covers k in {4l..4l+3} + {0,256,512,768} of NH=1024.
__global__ __launch_bounds__(256) void fc2_kernel(
    const float* __restrict__ h, const float* __restrict__ w2,
    const int* __restrict__ idx, float* __restrict__ out) {
    __shared__ int tok_lds[NT + NC];
    __shared__ int wsum[4];
    const int b  = blockIdx.x;
    const int th = b & 1;
    const int e  = (b >> 1) & 63;
    const int ch = b >> 7;
    const int tid = threadIdx.x, wave = tid >> 6, lane = tid & 63;
    const int nt = build_group(idx, e, tok_lds, wsum);
    const int start = th * 4;
    if (start >= nt) return;
    const float* w2e = w2 + (size_t)e * ND * NH;
    const int d0 = ch * 16 + wave * 4;

    for (int base = start; base < nt; base += 8) {
        float4 hb0[4], hb1[4], hb2[4], hb3[4];
#pragma unroll
        for (int t = 0; t < 4; ++t) {
            const float* hr = h + (size_t)tok_lds[base + t] * NH;
            hb0[t] = *(const float4*)(hr + lane * 4);
            hb1[t] = *(const float4*)(hr + 256 + lane * 4);
            hb2[t] = *(const float4*)(hr + 512 + lane * 4);
            hb3[t] = *(const float4*)(hr + 768 + lane * 4);
        }
#pragma unroll 4
        for (int r = 0; r < 4; ++r) {
            const float* wr = w2e + (size_t)(d0 + r) * NH;
            const float4 w0 = *(const float4*)(wr + lane * 4);
            const float4 w1v = *(const float4*)(wr + 256 + lane * 4);
            const float4 w2v = *(const float4*)(wr + 512 + lane * 4);
            const float4 w3v = *(const float4*)(wr + 768 + lane * 4);
            float acc[4];
#pragma unroll
            for (int t = 0; t < 4; ++t) {
                acc[t] = w0.x * hb0[t].x + w0.y * hb0[t].y + w0.z * hb0[t].z + w0.w * hb0[t].w
                       + w1v.x * hb1[t].x + w1v.y * hb1[t].y + w1v.z * hb1[t].z + w1v.w * hb1[t].w
                       + w2v.x * hb2[t].x + w2v.y * hb2[t].y + w2v.z * hb2[t].z + w2v.w * hb2[t].w
                       + w3v.x * hb3[t].x + w3v.y * hb3[t].y + w3v.z * hb3[t].z + w3v.w * hb3[t].w;
            }
            float p = fused_reduce4_64(acc, lane);
            if (lane < 4) {
                int t = ((lane & 1) << 1) | ((lane >> 1) & 1);
                int slot = base + t;
                if (slot < nt) {
                    int tk = tok_lds[slot];
                    out[(size_t)tk * ND + (d0 + r)] = p;
                }
            }
        }
    }
}

extern "C" void kernel_launch(void* const* d_in, const int* in_sizes, int n_in,
                              void* d_out, int out_size, void* d_ws, size_t ws_size,
                              hipStream_t stream) {
    const float* x    = (const float*)d_in[0];
    const int*   eidx = (const int*)d_in[1];
    const float* fc1w = (const float*)d_in[2];
    const float* fc2w = (const float*)d_in[3];
    float* out = (float*)d_out;
    float* h   = (float*)d_ws;

    fc1_kernel<<<NE * 32 * 2, 256, 0, stream>>>(x, fc1w, eidx, h);
    fc2_kernel<<<NE * 32 * 2, 256, 0, stream>>>(h, fc2w, eidx, out);
}

// Round 7
// 60.261 us; speedup vs baseline: 1.3470x; 1.3470x over previous
//
#include <hip/hip_runtime.h>
#include <math.h>

#define NE 64
#define ND 512
#define NH 1024
#define NT 256
#define NC 8   // pad amount in build_group (max token slots touched per pass)

// ws layout: h[NT*NH] floats

__device__ __forceinline__ int build_group(const int* __restrict__ idx, int e,
                                           int* tok_lds, int* wsum) {
    const int t = threadIdx.x, wave = t >> 6, lane = t & 63;
    const bool m = (idx[t] == e);
    const unsigned long long mask = __ballot(m);
    if (lane == 0) wsum[wave] = __popcll(mask);
    __syncthreads();
    int before = 0;
#pragma unroll
    for (int w = 0; w < 3; ++w) before += (w < wave) ? wsum[w] : 0;
    const int nt = wsum[0] + wsum[1] + wsum[2] + wsum[3];
    if (m) {
        int pos = before + __popcll(mask & ((1ull << lane) - 1ull));
        tok_lds[pos] = t;
    }
    __syncthreads();
    // pad so fragment loads are unconditional (dupes of token 0; stores stay
    // guarded by nt, so pad results are discarded)
    if (nt > 0 && t >= nt && t < nt + NC) tok_lds[t] = tok_lds[0];
    __syncthreads();
    return nt;
}

// Fused butterfly over 8 accumulators: 10 shuffles, depth 6, for 8 full
// 64-lane reductions. On exit lanes 0..7 hold the sum for token bitrev3(lane).
__device__ __forceinline__ float fused_reduce8_64(float v[NC], int lane) {
#pragma unroll
    for (int i = 0; i < 4; ++i) {
        float lo = v[i], hi = v[i + 4];
        float send = (lane & 1) ? lo : hi;
        float recv = __shfl_xor(send, 1);
        v[i] = ((lane & 1) ? hi : lo) + recv;
    }
#pragma unroll
    for (int i = 0; i < 2; ++i) {
        float lo = v[i], hi = v[i + 2];
        float send = (lane & 2) ? lo : hi;
        float recv = __shfl_xor(send, 2);
        v[i] = ((lane & 2) ? hi : lo) + recv;
    }
    {
        float lo = v[0], hi = v[1];
        float send = (lane & 4) ? lo : hi;
        float recv = __shfl_xor(send, 4);
        v[0] = ((lane & 4) ? hi : lo) + recv;
    }
    v[0] += __shfl_xor(v[0], 8);
    v[0] += __shfl_xor(v[0], 16);
    v[0] += __shfl_xor(v[0], 32);
    return v[0];
}

// Fused butterfly over 4 accumulators -> full 64-lane sums.
// On exit lane l holds the sum for token t = 2*(l&1) + ((l>>1)&1).
__device__ __forceinline__ float fused_reduce4_64(float v[4], int lane) {
#pragma unroll
    for (int i = 0; i < 2; ++i) {
        float lo = v[i], hi = v[i + 2];
        float send = (lane & 1) ? lo : hi;
        float recv = __shfl_xor(send, 1);
        v[i] = ((lane & 1) ? hi : lo) + recv;
    }
    {
        float lo = v[0], hi = v[1];
        float send = (lane & 2) ? lo : hi;
        float recv = __shfl_xor(send, 2);
        v[0] = ((lane & 2) ? hi : lo) + recv;
    }
    v[0] += __shfl_xor(v[0], 4);
    v[0] += __shfl_xor(v[0], 8);
    v[0] += __shfl_xor(v[0], 16);
    v[0] += __shfl_xor(v[0], 32);
    return v[0];
}

// fc1: grid = NE*32; block owns 32 H-rows (4 waves x 8 rows), all token
// slots in chunks of 8. Lane covers k in [4l,4l+4) and [256+4l,256+4l+4).
__global__ __launch_bounds__(256) void fc1_kernel(
    const float* __restrict__ x, const float* __restrict__ w1,
    const int* __restrict__ idx, float* __restrict__ h) {
    __shared__ int tok_lds[NT + NC];
    __shared__ int wsum[4];
    const int e  = blockIdx.x >> 5;
    const int ch = blockIdx.x & 31;
    const int tid = threadIdx.x, wave = tid >> 6, lane = tid & 63;
    const int nt = build_group(idx, e, tok_lds, wsum);
    if (nt == 0) return;
    const float* w1e = w1 + (size_t)e * NH * ND;
    const int jw = ch * 32 + wave * 8;

    for (int base = 0; base < nt; base += NC) {
        float4 xa[NC], xb[NC];
#pragma unroll
        for (int t = 0; t < NC; ++t) {
            const float* xr = x + (size_t)tok_lds[base + t] * ND;
            xa[t] = *(const float4*)(xr + lane * 4);
            xb[t] = *(const float4*)(xr + 256 + lane * 4);
        }
#pragma unroll 4
        for (int r = 0; r < 8; ++r) {
            const float* wr = w1e + (size_t)(jw + r) * ND;
            const float4 wa = *(const float4*)(wr + lane * 4);
            const float4 wb = *(const float4*)(wr + 256 + lane * 4);
            float acc[NC];
#pragma unroll
            for (int t = 0; t < NC; ++t) {
                acc[t] = wa.x * xa[t].x + wa.y * xa[t].y + wa.z * xa[t].z + wa.w * xa[t].w
                       + wb.x * xb[t].x + wb.y * xb[t].y + wb.z * xb[t].z + wb.w * xb[t].w;
            }
            float p = fused_reduce8_64(acc, lane);
            if (lane < NC) {
                int t = ((lane & 1) << 2) | (lane & 2) | ((lane >> 2) & 1);
                if (base + t < nt) {
                    int tk = tok_lds[base + t];
                    float s = p / (1.0f + __expf(-p));
                    h[(size_t)tk * NH + (jw + r)] = s;
                }
            }
        }
    }
}

// fc2: grid = NE*32; block owns 16 D-rows. Each wave owns 4 d-rows and ALL
// tokens of the current 4-token chunk -> all 4 waves stream weights even for
// nt<=4 (63% of experts). nt>4 loops again over the SAME 64KB W2 chunk:
// re-read hits L1/L2 on this CU (in-block token split; cross-block split
// duplicated HBM traffic and regressed in R6).
// Lane covers k in {4l..4l+3} + {0,256,512,768} of NH=1024.
__global__ __launch_bounds__(256) void fc2_kernel(
    const float* __restrict__ h, const float* __restrict__ w2,
    const int* __restrict__ idx, float* __restrict__ out) {
    __shared__ int tok_lds[NT + NC];
    __shared__ int wsum[4];
    const int e  = blockIdx.x >> 5;
    const int ch = blockIdx.x & 31;
    const int tid = threadIdx.x, wave = tid >> 6, lane = tid & 63;
    const int nt = build_group(idx, e, tok_lds, wsum);
    if (nt == 0) return;
    const float* w2e = w2 + (size_t)e * ND * NH;
    const int d0 = ch * 16 + wave * 4;

    for (int base = 0; base < nt; base += 4) {
        float4 hb0[4], hb1[4], hb2[4], hb3[4];
#pragma unroll
        for (int t = 0; t < 4; ++t) {
            const float* hr = h + (size_t)tok_lds[base + t] * NH;
            hb0[t] = *(const float4*)(hr + lane * 4);
            hb1[t] = *(const float4*)(hr + 256 + lane * 4);
            hb2[t] = *(const float4*)(hr + 512 + lane * 4);
            hb3[t] = *(const float4*)(hr + 768 + lane * 4);
        }
#pragma unroll
        for (int r = 0; r < 4; ++r) {
            const float* wr = w2e + (size_t)(d0 + r) * NH;
            const float4 w0 = *(const float4*)(wr + lane * 4);
            const float4 w1v = *(const float4*)(wr + 256 + lane * 4);
            const float4 w2v = *(const float4*)(wr + 512 + lane * 4);
            const float4 w3v = *(const float4*)(wr + 768 + lane * 4);
            float acc[4];
#pragma unroll
            for (int t = 0; t < 4; ++t) {
                acc[t] = w0.x * hb0[t].x + w0.y * hb0[t].y + w0.z * hb0[t].z + w0.w * hb0[t].w
                       + w1v.x * hb1[t].x + w1v.y * hb1[t].y + w1v.z * hb1[t].z + w1v.w * hb1[t].w
                       + w2v.x * hb2[t].x + w2v.y * hb2[t].y + w2v.z * hb2[t].z + w2v.w * hb2[t].w
                       + w3v.x * hb3[t].x + w3v.y * hb3[t].y + w3v.z * hb3[t].z + w3v.w * hb3[t].w;
            }
            float p = fused_reduce4_64(acc, lane);
            if (lane < 4) {
                int t = ((lane & 1) << 1) | ((lane >> 1) & 1);
                int slot = base + t;
                if (slot < nt) {
                    int tk = tok_lds[slot];
                    out[(size_t)tk * ND + (d0 + r)] = p;
                }
            }
        }
    }
}

extern "C" void kernel_launch(void* const* d_in, const int* in_sizes, int n_in,
                              void* d_out, int out_size, void* d_ws, size_t ws_size,
                              hipStream_t stream) {
    const float* x    = (const float*)d_in[0];
    const int*   eidx = (const int*)d_in[1];
    const float* fc1w = (const float*)d_in[2];
    const float* fc2w = (const float*)d_in[3];
    float* out = (float*)d_out;
    float* h   = (float*)d_ws;

    fc1_kernel<<<NE * 32, 256, 0, stream>>>(x, fc1w, eidx, h);
    fc2_kernel<<<NE * 32, 256, 0, stream>>>(h, fc2w, eidx, out);
}